// Round 15
// baseline (138.918 us; speedup 1.0000x reference)
//
#include <hip/hip_runtime.h>
#include <stdint.h>

#define B_  4
#define NQ_ 2048
#define NP_ 8192
#define D_  256
#define F_  40
#define K_  16

// ---------------- Kernel 1: hash codes -------------------------------------
// v12 = v11 (LDS-broadcast proj) with UNROLL DISCIPLINE. v11's failure was
// codegen, not the theory: full unroll of c(4) x d4(16) x f(5) -> 320-deep
// body, ds_read results hoisted, VGPR 128 + 98.8MB scratch. Fix: unroll 1
// on c, unroll 2 on d4, proj float4 loaded immediately before its 4 fmas
// (live window ~30 VGPR). Proj (40KB) staged once per block; inner reads
// are wave-uniform ds_read_b128 BROADCASTS (no scalar queue, no K$ thrash
// — the v9-convicted path). Vector staging = v7 chunked double-buffer
// (34.8KB). LDS 76KB -> 2 blocks/CU = 16 waves/CU (same occupancy as v5;
// VGPR<=128 free at this LDS ceiling). Accumulation d=0..255 sequential
// per feature (bit-exact). 512 thr, 8 waves x 5 features, lane = vector.
// Pre-committed: hash<28us = win; hash>=30us or WRITE>10MB = revert next.
__global__ __launch_bounds__(512) void hash_kernel(
    const float* __restrict__ qp, const float* __restrict__ pp,
    const float* __restrict__ proj, uint64_t* __restrict__ qcodes,
    uint64_t* __restrict__ pcodes) {
  __shared__ float buf[2][64][68];        // 34.8 KB vector double buffer
  __shared__ float psh[F_ * 256];         // 40 KB proj (f-major)
  __shared__ unsigned short cbuf[64][8];  // 1 KB combine buffer
  int t = threadIdx.x;
  int v0 = blockIdx.x * 64;  // first vector in concat [queries; points] space
  bool isQ = v0 < B_ * NQ_;  // B*NQ = 8192 = 128 blocks: clean split
  const float* src =
      isQ ? (qp + (size_t)v0 * D_) : (pp + (size_t)(v0 - B_ * NQ_) * D_);
  const float4* src4 = (const float4*)src;  // rows are 1KB-aligned

  int lane = t & 63, w = t >> 6;  // 8 waves
  int fb = w * 5;                 // this wave's first feature

  // Stage chunk c into buf[c&1]: 64 vec x 16 float4 = 1024 float4, 512 thr
  // -> 2 each. idx=i*512+t: v=idx>>4, f4=idx&15.
#define STAGE(c)                                              \
  {                                                           \
    _Pragma("unroll")                                         \
    for (int i = 0; i < 2; ++i) {                             \
      int idx = i * 512 + t;                                  \
      int v = idx >> 4, f4 = idx & 15;                        \
      float4 x = src4[v * 64 + (c) * 16 + f4];                \
      *(float4*)&buf[(c) & 1][v][4 * f4] = x;                 \
    }                                                         \
  }

  // Stage all of proj once: 2560 float4, 512 threads -> 5 each, coalesced.
  {
    const float4* proj4 = (const float4*)proj;
    float4* psh4 = (float4*)psh;
#pragma unroll
    for (int i = 0; i < 5; ++i) psh4[i * 512 + t] = proj4[i * 512 + t];
  }

  float acc[5];
#pragma unroll
  for (int f = 0; f < 5; ++f) acc[f] = 0.0f;

  STAGE(0);
  __syncthreads();
#pragma unroll 1
  for (int c = 0; c < 4; ++c) {
    if (c < 3) STAGE(c + 1);  // overlaps compute(c); drains at the barrier
    const float4* row4 = (const float4*)&buf[c & 1][lane][0];
    const float* pw = &psh[fb * 256 + c * 64];  // wave-uniform base
#pragma unroll 2
    for (int d4 = 0; d4 < 16; ++d4) {
      float4 x4 = row4[d4];  // per-lane ds_read_b128
#pragma unroll
      for (int f = 0; f < 5; ++f) {
        // Wave-uniform address -> LDS broadcast read; consumed immediately.
        float4 p = *(const float4*)(pw + f * 256 + 4 * d4);
        // x,y,z,w with d4 then c ascending == d 0..255 per feature.
        acc[f] = fmaf(x4.x, p.x, acc[f]);
        acc[f] = fmaf(x4.y, p.y, acc[f]);
        acc[f] = fmaf(x4.z, p.z, acc[f]);
        acc[f] = fmaf(x4.w, p.w, acc[f]);
      }
    }
    __syncthreads();  // compute(c) readers done + stage(c+1) writes landed
  }
#undef STAGE

  unsigned bits = 0;
#pragma unroll
  for (int f = 0; f < 5; ++f)
    if (acc[f] > 0.0f) bits |= 1u << f;

  // Combine the 8 waves' 5-bit chunks per vector.
  cbuf[lane][w] = (unsigned short)bits;
  __syncthreads();
  if (w == 0) {
    uint64_t code = 0;
#pragma unroll
    for (int j = 0; j < 8; ++j)
      code |= (uint64_t)cbuf[lane][j] << (5 * j);
    int gv = v0 + lane;
    if (isQ) qcodes[gv] = code;
    else pcodes[gv - B_ * NQ_] = code;
  }
}

// ---------------- Kernel 2: exact top-16 by (dist, index) -------------------
// v4 (unchanged, HW-verified absmax 0.0): nibble cache in LDS (4KB/wave),
// codes streamed from global (64KB/batch, L2-resident), zero __syncthreads,
// launch_bounds(512,8) -> 4 blocks/CU = 32 waves/CU.
__global__ __launch_bounds__(512, 8) void select_kernel(
    const uint64_t* __restrict__ qcodes, const uint64_t* __restrict__ pcodes,
    float* __restrict__ outIdx, float* __restrict__ outDist) {
  __shared__ unsigned nib[8 * 1024];  // 32 KB: 8 waves x 4KB nibble cache
  __shared__ unsigned keybuf[8][K_];

  int tid = threadIdx.x;
  int w = tid >> 6, lane = tid & 63;
  int qg = blockIdx.x * 8 + w;  // global query id
  int bb = blockIdx.x >> 8;     // 256 blocks per batch
  const ulonglong2* pb2 = (const ulonglong2*)(pcodes + (size_t)bb * NP_);
  uint64_t qc = qcodes[qg];
  unsigned* nibw = nib + w * 1024;
  const uint64_t M = 0x00FF00FF00FF00FFull;

  // ---- Pass 1: stream codes from L2; nibble cache + merged-bin hist ----
  uint64_t cf = 0;
  unsigned accum = 0;
#pragma unroll 4
  for (int j2 = 0; j2 < 64; ++j2) {
    ulonglong2 pc = pb2[j2 * 64 + lane];  // coalesced 16B, L2-hot
    unsigned d0 = (unsigned)__popcll(qc ^ pc.x);
    unsigned d1 = (unsigned)__popcll(qc ^ pc.y);
    unsigned c0 = d0 < 15u ? d0 : 15u;
    unsigned c1 = d1 < 15u ? d1 : 15u;
    accum |= (c0 | (c1 << 4)) << (8 * (j2 & 3));
    int r0 = (int)d0 - 8; r0 = r0 < 0 ? 0 : (r0 > 7 ? 7 : r0);  // v_med3
    int r1 = (int)d1 - 8; r1 = r1 < 0 ? 0 : (r1 > 7 ? 7 : r1);
    cf += (1ull << (r0 << 3)) + (1ull << (r1 << 3));  // bytes <=128: safe
    if ((j2 & 3) == 3) {
      nibw[lane + 64 * (j2 >> 2)] = accum;  // bank lane%32: 2-way, free
      accum = 0;
    }
  }
  uint64_t e = cf & M, o = (cf >> 8) & M;
#pragma unroll
  for (int s = 1; s < 64; s <<= 1) {
    e += __shfl_xor(e, s);
    o += __shfl_xor(o, s);
  }

  int t = 0;
  unsigned n_lt = 0;
  int rfound = -1;
  {
    unsigned cum = 0;
#pragma unroll
    for (int r = 0; r < 8; ++r) {
      unsigned c = (unsigned)(((r & 1) ? o : e) >> ((r >> 1) * 16)) & 0xFFFFu;
      if (rfound < 0 && cum + c >= K_) { rfound = r; t = 8 + r; n_lt = cum; }
      cum += c;
    }
  }
  uint64_t lmask = (1ull << lane) - 1;

  if (rfound >= 1 && rfound <= 6) {
    // ---- Pass 3 (fast): LDS nibble scan, pair-ordered collection ----
    unsigned r_need = K_ - n_lt;
    unsigned cl = 0, ce = 0;
    unsigned ut = (unsigned)t;
#pragma unroll 4
    for (int k = 0; k < 16; ++k) {
      unsigned dw = nibw[lane + 64 * k];
#pragma unroll
      for (int b = 0; b < 4; ++b) {
        unsigned d0 = (dw >> (8 * b)) & 0xFu;
        unsigned d1 = (dw >> (8 * b + 4)) & 0xFu;
        int p0 = (4 * k + b) * 128 + 2 * lane;
        uint64_t m0 = __ballot(d0 < ut);
        uint64_t m1 = __ballot(d1 < ut);
        if (m0 | m1) {
          unsigned base = cl + (unsigned)__popcll(m0 & lmask) +
                          (unsigned)__popcll(m1 & lmask);
          if (d0 < ut) keybuf[w][base] = (d0 << 13) | (unsigned)p0;
          if (d1 < ut)
            keybuf[w][base + (unsigned)((m0 >> lane) & 1)] =
                (d1 << 13) | (unsigned)(p0 + 1);
          cl += (unsigned)__popcll(m0) + (unsigned)__popcll(m1);
        }
        if (ce < r_need) {  // wave-uniform: skipped once eq quota filled
          uint64_t q0 = __ballot(d0 == ut);
          uint64_t q1 = __ballot(d1 == ut);
          if (q0 | q1) {
            unsigned b2 = ce + (unsigned)__popcll(q0 & lmask) +
                          (unsigned)__popcll(q1 & lmask);
            unsigned pos1 = b2 + (unsigned)((q0 >> lane) & 1);
            if (d0 == ut && b2 < r_need)
              keybuf[w][n_lt + b2] = (ut << 13) | (unsigned)p0;
            if (d1 == ut && pos1 < r_need)
              keybuf[w][n_lt + pos1] = (ut << 13) | (unsigned)(p0 + 1);
            ce += (unsigned)__popcll(q0) + (unsigned)__popcll(q1);
          }
        }
      }
    }
  } else {
    // ---- Exact fallback (cold, prob ~0): global re-scan, 3-pass ----
    const uint64_t* pbl = pcodes + (size_t)bb * NP_;
    uint64_t c8 = 0;
#pragma unroll 4
    for (int j = 0; j < 64; ++j) {
      ulonglong2 pc = pb2[j * 64 + lane];
      int d0 = __popcll(qc ^ pc.x);
      int d1 = __popcll(qc ^ pc.y);
      c8 += (1ull << (d0 & 56)) + (1ull << (d1 & 56));  // (d>>3)*8 == d&56
    }
    uint64_t e2 = c8 & M, o2 = (c8 >> 8) & M;
#pragma unroll
    for (int s = 1; s < 64; s <<= 1) {
      e2 += __shfl_xor(e2, s);
      o2 += __shfl_xor(o2, s);
    }
    int Bb = 0;
    unsigned nbefore = 0, cum = 0;
    bool found = false;
#pragma unroll
    for (int k2 = 0; k2 < 6; ++k2) {
      unsigned c = (unsigned)(((k2 & 1) ? o2 : e2) >> ((k2 >> 1) * 16)) & 0xFFFFu;
      if (!found && cum + c >= K_) { Bb = k2; nbefore = cum; found = true; }
      cum += c;
    }
    int base = Bb * 8;
    uint64_t cff = 0;
#pragma unroll 4
    for (int j = 0; j < 64; ++j) {
      ulonglong2 pc = pb2[j * 64 + lane];
      unsigned r0 = (unsigned)(__popcll(qc ^ pc.x) - base);
      unsigned r1 = (unsigned)(__popcll(qc ^ pc.y) - base);
      if (r0 < 8u) cff += 1ull << (r0 << 3);
      if (r1 < 8u) cff += 1ull << (r1 << 3);
    }
    uint64_t ef = cff & M, of = (cff >> 8) & M;
#pragma unroll
    for (int s = 1; s < 64; s <<= 1) {
      ef += __shfl_xor(ef, s);
      of += __shfl_xor(of, s);
    }
    unsigned cum2 = nbefore;
    bool f2 = false;
#pragma unroll
    for (int r = 0; r < 8; ++r) {
      unsigned c = (unsigned)(((r & 1) ? of : ef) >> ((r >> 1) * 16)) & 0xFFFFu;
      if (!f2 && cum2 + c >= K_) { t = base + r; n_lt = cum2; f2 = true; }
      cum2 += c;
    }
    unsigned r_need = K_ - n_lt;
    unsigned cl = 0, ce = 0;
    for (int j = 0; j < 128; ++j) {
      int p = j * 64 + lane;
      int d = __popcll(qc ^ pbl[p]);
      if (__any(d <= t)) {
        bool blt = (d < t), beq = (d == t);
        uint64_t mlt = __ballot(blt), meq = __ballot(beq);
        if (blt)
          keybuf[w][cl + (unsigned)__popcll(mlt & lmask)] =
              ((unsigned)d << 13) | (unsigned)p;
        if (beq) {
          unsigned pos = ce + (unsigned)__popcll(meq & lmask);
          if (pos < r_need)
            keybuf[w][n_lt + pos] = ((unsigned)d << 13) | (unsigned)p;
        }
        cl += (unsigned)__popcll(mlt);
        ce += (unsigned)__popcll(meq);
      }
    }
  }

  // ---- rank-sort the 16 keys (distinct: idx embedded) and emit ----
  // keybuf[w] written and read by the SAME wave: no block sync needed.
  if (lane < K_) {
    unsigned my = keybuf[w][lane];
    int rank = 0;
#pragma unroll
    for (int jj = 0; jj < K_; ++jj) rank += (keybuf[w][jj] < my) ? 1 : 0;
    int off = qg * K_ + rank;
    outIdx[off]  = (float)(my & 8191u);  // index
    outDist[off] = (float)(my >> 13);    // distance
  }
}

extern "C" void kernel_launch(void* const* d_in, const int* in_sizes, int n_in,
                              void* d_out, int out_size, void* d_ws, size_t ws_size,
                              hipStream_t stream) {
  const float* qp   = (const float*)d_in[0];
  const float* pp   = (const float*)d_in[1];
  const float* proj = (const float*)d_in[2];
  // d_in[3] is k (always 16) — hardcoded.

  uint64_t* pcodes = (uint64_t*)d_ws;            // B*NP u64
  uint64_t* qcodes = pcodes + (size_t)B_ * NP_;  // B*NQ u64

  float* outIdx  = (float*)d_out;                   // B*NQ*K indices (as float)
  float* outDist = outIdx + (size_t)B_ * NQ_ * K_;  // B*NQ*K distances

  int total_vecs = B_ * (NQ_ + NP_);  // 40960
  hash_kernel<<<total_vecs / 64, 512, 0, stream>>>(qp, pp, proj, qcodes, pcodes);
  select_kernel<<<B_ * NQ_ / 8, 512, 0, stream>>>(qcodes, pcodes, outIdx, outDist);
}